// Round 1
// baseline (178.214 us; speedup 1.0000x reference)
//
#include <hip/hip_runtime.h>
#include <hip/hip_bf16.h>
#include <stdint.h>

// Problem constants (from reference setup_inputs)
#define B_    32
#define C_    256
#define HW_   16384          // 128*128
#define K_TOP 1638           // int(16384 * 0.1)

// ---------------------------------------------------------------------------
// Kernel 1: scores[b, hw] = | sum_c x[b,c,hw] * w[c] + bias |
// One thread computes 4 consecutive hw positions via float4 loads.
// Grid: B*HW/4 threads = 131072 -> 512 blocks x 256 threads.
// Memory: reads 512 MiB of x exactly once, fully coalesced (hw contiguous).
// ---------------------------------------------------------------------------
__global__ __launch_bounds__(256) void score_kernel(const float* __restrict__ x,
                                                    const float* __restrict__ w,
                                                    const float* __restrict__ bias,
                                                    float* __restrict__ scores) {
    __shared__ float ws[C_];
    for (int i = threadIdx.x; i < C_; i += blockDim.x) ws[i] = w[i];
    __syncthreads();

    const int tid = blockIdx.x * blockDim.x + threadIdx.x;   // 0 .. 131071
    const int bi  = tid >> 12;                               // tid / 4096 (threads per batch)
    const int p4  = (tid & 4095) << 2;                       // spatial position * 4

    const float* xb = x + (size_t)bi * C_ * HW_ + p4;

    float a0 = 0.f, a1 = 0.f, a2 = 0.f, a3 = 0.f;
    #pragma unroll 8
    for (int c = 0; c < C_; ++c) {
        const float4 v = *reinterpret_cast<const float4*>(xb + (size_t)c * HW_);
        const float wc = ws[c];
        a0 = fmaf(v.x, wc, a0);
        a1 = fmaf(v.y, wc, a1);
        a2 = fmaf(v.z, wc, a2);
        a3 = fmaf(v.w, wc, a3);
    }

    const float bb = bias[0];
    float4 o;
    o.x = fabsf(a0 + bb);
    o.y = fabsf(a1 + bb);
    o.z = fabsf(a2 + bb);
    o.w = fabsf(a3 + bb);
    *reinterpret_cast<float4*>(scores + (size_t)bi * HW_ + p4) = o;
}

// ---------------------------------------------------------------------------
// Kernel 2: per-batch exact top-K mean via radix select on float bit pattern.
// Non-negative fp32 values are order-isomorphic to their uint32 bits, so a
// 4-pass MSB-first 8-bit radix select finds T = the K-th largest value
// exactly. mean = (sum_{v>T} v + (K - count_{>T}) * T) / K  (exact w/ ties).
// One block (256 threads) per batch; scores are L2-resident (2 MiB total).
// ---------------------------------------------------------------------------
__global__ __launch_bounds__(256) void topk_mean_kernel(const float* __restrict__ scores,
                                                        float* __restrict__ out) {
    const int b = blockIdx.x;
    const uint32_t* s = reinterpret_cast<const uint32_t*>(scores) + (size_t)b * HW_;

    __shared__ uint32_t hist[256];
    __shared__ uint32_t sh_prefix;
    __shared__ int      sh_k;
    __shared__ float    red_s[4];
    __shared__ int      red_c[4];

    int k = K_TOP;
    uint32_t prefix = 0;

    for (int shift = 24; shift >= 0; shift -= 8) {
        for (int i = threadIdx.x; i < 256; i += blockDim.x) hist[i] = 0;
        __syncthreads();

        const uint32_t mask = (shift == 24) ? 0u : (0xFFFFFFFFu << (shift + 8));
        for (int i = threadIdx.x; i < HW_; i += blockDim.x) {
            const uint32_t v = s[i];
            if ((v & mask) == (prefix & mask))
                atomicAdd(&hist[(v >> shift) & 255u], 1u);
        }
        __syncthreads();

        if (threadIdx.x == 0) {
            int cum = 0, bin = 255;
            for (; bin > 0; --bin) {
                const int c = (int)hist[bin];
                if (cum + c >= k) break;
                cum += c;
            }
            sh_prefix = prefix | ((uint32_t)bin << shift);
            sh_k = k - cum;
        }
        __syncthreads();
        prefix = sh_prefix;
        k = sh_k;
        __syncthreads();   // hist reused next pass
    }

    const float T = __uint_as_float(prefix);

    float sum = 0.f;
    int   cnt = 0;
    for (int i = threadIdx.x; i < HW_; i += blockDim.x) {
        const float v = __uint_as_float(s[i]);
        if (v > T) { sum += v; cnt++; }
    }

    // wave (64-lane) reduction, then cross-wave via LDS
    #pragma unroll
    for (int off = 32; off > 0; off >>= 1) {
        sum += __shfl_down(sum, off);
        cnt += __shfl_down(cnt, off);
    }
    const int lane = threadIdx.x & 63;
    const int wid  = threadIdx.x >> 6;
    if (lane == 0) { red_s[wid] = sum; red_c[wid] = cnt; }
    __syncthreads();

    if (threadIdx.x == 0) {
        float ts = 0.f;
        int   tc = 0;
        #pragma unroll
        for (int i = 0; i < 4; ++i) { ts += red_s[i]; tc += red_c[i]; }
        out[b] = (ts + (float)(K_TOP - tc) * T) / (float)K_TOP;
    }
}

// ---------------------------------------------------------------------------
extern "C" void kernel_launch(void* const* d_in, const int* in_sizes, int n_in,
                              void* d_out, int out_size, void* d_ws, size_t ws_size,
                              hipStream_t stream) {
    const float* x    = (const float*)d_in[0];   // [32,256,128,128]
    const float* w    = (const float*)d_in[1];   // [1,256,1,1] -> 256 floats
    const float* bias = (const float*)d_in[2];   // [1]
    float*       out  = (float*)d_out;           // [32]
    float*       scores = (float*)d_ws;          // 32*16384 floats = 2 MiB scratch

    const int total_threads = B_ * (HW_ / 4);    // 131072
    score_kernel<<<total_threads / 256, 256, 0, stream>>>(x, w, bias, scores);
    topk_mean_kernel<<<B_, 256, 0, stream>>>(scores, out);
}

// Round 2
// 102.898 us; speedup vs baseline: 1.7319x; 1.7319x over previous
//
#include <hip/hip_runtime.h>
#include <hip/hip_bf16.h>
#include <stdint.h>

// Problem constants (from reference setup_inputs)
#define B_    32
#define C_    256
#define HW_   16384          // 128*128
#define K_TOP 1638           // int(16384 * 0.1)

typedef float f32x2 __attribute__((ext_vector_type(2)));
typedef float f32x4 __attribute__((ext_vector_type(4)));

// ---------------------------------------------------------------------------
// Kernel 1: scores[b, hw] = | sum_c x[b,c,hw] * w[c] + bias |
// - thread-divergent part of the address (toff) is a fixed 32-bit VGPR offset;
//   the per-channel advance is on the wave-uniform base pointer -> SADDR loads
//   with scalar (SALU) base increments.
// - w[c] is uniform -> s_load; broadcast into an SGPR pair for v_pk_fma_f32
//   (2 packed FMAs per instruction, w read as the single scalar operand).
// ---------------------------------------------------------------------------
__global__ __launch_bounds__(256) void score_kernel(const float* __restrict__ x,
                                                    const float* __restrict__ w,
                                                    const float* __restrict__ bias,
                                                    float* __restrict__ scores) {
    const uint32_t tid  = blockIdx.x * 256u + threadIdx.x;   // 0 .. 131071
    const uint32_t bi   = tid >> 12;                         // batch
    const uint32_t p4   = (tid & 4095u) << 2;                // position*4
    const uint32_t toff = bi * (uint32_t)(C_ * HW_) + p4;    // element offset (fits 32b)

    const float* xc = x;                                     // wave-uniform, advances by HW_
    f32x2 a0 = {0.f, 0.f};
    f32x2 a1 = {0.f, 0.f};

    #pragma unroll 8
    for (int c = 0; c < C_; ++c) {
        const f32x4 v  = *reinterpret_cast<const f32x4*>(xc + toff);
        const float wc = w[c];                               // uniform -> s_load
        const f32x2 wp = {wc, wc};                           // SGPR pair (SALU movs)
        f32x2 lo = __builtin_shufflevector(v, v, 0, 1);
        f32x2 hi = __builtin_shufflevector(v, v, 2, 3);
        asm("v_pk_fma_f32 %0, %1, %2, %0" : "+v"(a0) : "v"(lo), "s"(wp));
        asm("v_pk_fma_f32 %0, %1, %2, %0" : "+v"(a1) : "v"(hi), "s"(wp));
        xc += HW_;
    }

    const float bb = bias[0];
    f32x4 o;
    o[0] = fabsf(a0[0] + bb);
    o[1] = fabsf(a0[1] + bb);
    o[2] = fabsf(a1[0] + bb);
    o[3] = fabsf(a1[1] + bb);
    *reinterpret_cast<f32x4*>(scores + (bi * (uint32_t)HW_ + p4)) = o;
}

// ---------------------------------------------------------------------------
// Wave-parallel crossing-bin finder. hist has NB bins (NB in {2048, 512});
// finds bin B s.t. suffix_count(B+1) < k <= suffix_count(B).
// Two-level: 64 lanes each sum NB/64 bins (rotated, conflict-lite), suffix
// scan across lanes via shfl, then suffix scan inside the winning group.
// Writes *sh_bin = B, *sh_k = k - suffix_count(B+1). ~300 cycles.
// ---------------------------------------------------------------------------
template <int NB>
__device__ __forceinline__ void find_crossing(const uint32_t* hist, int k,
                                              int* sh_bin, int* sh_k, int tid) {
    constexpr int G = NB >> 6;                      // bins per lane (32 or 8)
    if (tid < 64) {
        const int lane = tid;
        uint32_t gs = 0;
        #pragma unroll
        for (int i = 0; i < G; ++i) {
            const int j = (i + lane) & (G - 1);     // rotate to spread banks
            gs += hist[lane * G + j];
        }
        // suffix sum across 64 lanes: s[l] = sum_{j>=l} gs[j]
        uint32_t s = gs;
        #pragma unroll
        for (int off = 1; off < 64; off <<= 1) {
            uint32_t t = __shfl_down(s, off);
            s += (lane + off < 64) ? t : 0u;
        }
        uint32_t snext = __shfl_down(s, 1);
        if (lane == 63) snext = 0u;
        const bool mine = (s >= (uint32_t)k) && (snext < (uint32_t)k);
        const unsigned long long bal = __ballot(mine);
        const int g = __ffsll(bal) - 1;             // winning group (uniform)
        const uint32_t above_g = __shfl(snext, g);  // count strictly above group g

        // stage 2: suffix scan of the G bins inside group g
        uint32_t hv = (lane < G) ? hist[g * G + lane] : 0u;
        uint32_t s2 = hv;
        #pragma unroll
        for (int off = 1; off < G; off <<= 1) {
            uint32_t t = __shfl_down(s2, off);
            s2 += (lane + off < G) ? t : 0u;
        }
        uint32_t s2next = __shfl_down(s2, 1);
        if (lane >= G - 1) s2next = 0u;
        const bool mine2 = (lane < G) &&
                           (above_g + s2 >= (uint32_t)k) &&
                           (above_g + s2next < (uint32_t)k);
        if (mine2) {
            *sh_bin = g * G + lane;
            *sh_k   = k - (int)(above_g + s2next);
        }
    }
    __syncthreads();
}

// ---------------------------------------------------------------------------
// Kernel 2: per-batch exact top-K mean. One block (1024 thr, 16 waves) per
// batch. Each thread keeps its 16 values in registers for all passes.
// Radix levels over the 31-bit pattern: bits 30:20 (2048 bins) ->
// bits 19:9 (2048 bins) -> bits 8:0 (512 bins, counts+sums; all values in a
// final bin are bit-identical so float atomics are exact & deterministic).
// ---------------------------------------------------------------------------
__global__ __launch_bounds__(1024) void topk_mean_kernel(const float* __restrict__ scores,
                                                         float* __restrict__ out) {
    const int tid = threadIdx.x;
    const int b   = blockIdx.x;

    __shared__ uint32_t hist[2048];
    __shared__ float    sumc[512];
    __shared__ float    red[16];
    __shared__ int      sh_bin, sh_k;

    // ---- load this thread's 16 values into registers (coalesced uint4) ----
    const uint4* sv = reinterpret_cast<const uint4*>(scores) + (size_t)b * (HW_ / 4);
    uint32_t r[16];
    {
        uint4 q;
        q = sv[tid];        r[0]  = q.x; r[1]  = q.y; r[2]  = q.z; r[3]  = q.w;
        q = sv[tid + 1024]; r[4]  = q.x; r[5]  = q.y; r[6]  = q.z; r[7]  = q.w;
        q = sv[tid + 2048]; r[8]  = q.x; r[9]  = q.y; r[10] = q.z; r[11] = q.w;
        q = sv[tid + 3072]; r[12] = q.x; r[13] = q.y; r[14] = q.z; r[15] = q.w;
    }

    hist[tid] = 0u; hist[tid + 1024] = 0u;
    __syncthreads();

    // ---- pass A: bits 30:20 ----
    #pragma unroll
    for (int i = 0; i < 16; ++i) atomicAdd(&hist[r[i] >> 20], 1u);
    __syncthreads();
    find_crossing<2048>(hist, K_TOP, &sh_bin, &sh_k, tid);
    const uint32_t B1 = (uint32_t)sh_bin;
    const int      k1 = sh_k;
    __syncthreads();

    hist[tid] = 0u; hist[tid + 1024] = 0u;
    __syncthreads();

    // ---- pass B: bits 19:9 among prefix-B1; accumulate sum above B1 ----
    float sAbove = 0.f;
    #pragma unroll
    for (int i = 0; i < 16; ++i) {
        const uint32_t u  = r[i];
        const uint32_t b1 = u >> 20;
        if (b1 > B1)       sAbove += __uint_as_float(u);
        else if (b1 == B1) atomicAdd(&hist[(u >> 9) & 2047u], 1u);
    }
    __syncthreads();
    find_crossing<2048>(hist, k1, &sh_bin, &sh_k, tid);
    const uint32_t B2 = (uint32_t)sh_bin;
    const int      k2 = sh_k;
    __syncthreads();

    if (tid < 512) { hist[tid] = 0u; sumc[tid] = 0.f; }
    __syncthreads();

    // ---- pass C: bits 8:0 among prefix-(B1,B2); counts + exact sums ----
    #pragma unroll
    for (int i = 0; i < 16; ++i) {
        const uint32_t u = r[i];
        if ((u >> 20) == B1) {
            const uint32_t b2 = (u >> 9) & 2047u;
            if (b2 > B2) sAbove += __uint_as_float(u);
            else if (b2 == B2) {
                const uint32_t b3 = u & 511u;
                atomicAdd(&hist[b3], 1u);
                atomicAdd(&sumc[b3], __uint_as_float(u));
            }
        }
    }
    __syncthreads();
    find_crossing<512>(hist, k2, &sh_bin, &sh_k, tid);
    const uint32_t B3 = (uint32_t)sh_bin;
    const int      k3 = sh_k;
    __syncthreads();

    // values strictly above T that live in the last-level bins > B3
    if (tid < 512 && tid > (int)B3) sAbove += sumc[tid];

    // ---- block reduction of sAbove ----
    #pragma unroll
    for (int off = 32; off > 0; off >>= 1) sAbove += __shfl_down(sAbove, off);
    if ((tid & 63) == 0) red[tid >> 6] = sAbove;
    __syncthreads();

    if (tid == 0) {
        float tot = 0.f;
        #pragma unroll
        for (int i = 0; i < 16; ++i) tot += red[i];
        const float T = __uint_as_float((B1 << 20) | (B2 << 9) | B3);
        out[b] = (tot + (float)k3 * T) / (float)K_TOP;
    }
}

// ---------------------------------------------------------------------------
extern "C" void kernel_launch(void* const* d_in, const int* in_sizes, int n_in,
                              void* d_out, int out_size, void* d_ws, size_t ws_size,
                              hipStream_t stream) {
    const float* x    = (const float*)d_in[0];   // [32,256,128,128]
    const float* w    = (const float*)d_in[1];   // [1,256,1,1] -> 256 floats
    const float* bias = (const float*)d_in[2];   // [1]
    float*       out  = (float*)d_out;           // [32,1]
    float*       scores = (float*)d_ws;          // 2 MiB scratch

    score_kernel<<<512, 256, 0, stream>>>(x, w, bias, scores);
    topk_mean_kernel<<<B_, 1024, 0, stream>>>(scores, out);
}

// Round 3
// 95.884 us; speedup vs baseline: 1.8587x; 1.0732x over previous
//
#include <hip/hip_runtime.h>
#include <hip/hip_bf16.h>
#include <stdint.h>

// Problem constants (from reference setup_inputs)
#define B_    32
#define C_    256
#define HW_   16384          // 128*128
#define K_TOP 1638           // int(16384 * 0.1)

typedef float f32x2 __attribute__((ext_vector_type(2)));
typedef float f32x4 __attribute__((ext_vector_type(4)));

// ---------------------------------------------------------------------------
// Kernel 1: scores[b, hw] = | sum_c x[b,c,hw] * w[c] + bias |
// - x is 512 MiB stream-once data (2x the 256 MiB L3): load NON-TEMPORAL so
//   the stream doesn't allocate L1/L2/L3 lines (and doesn't evict the 2 MiB
//   scores buffer needed by kernel 2).
// - per-channel advance on the wave-uniform base pointer -> SADDR loads with
//   scalar base increments; w[c] uniform -> s_load; packed FMA via SGPR pair.
// ---------------------------------------------------------------------------
__global__ __launch_bounds__(256) void score_kernel(const float* __restrict__ x,
                                                    const float* __restrict__ w,
                                                    const float* __restrict__ bias,
                                                    float* __restrict__ scores) {
    const uint32_t tid  = blockIdx.x * 256u + threadIdx.x;   // 0 .. 131071
    const uint32_t bi   = tid >> 12;                         // batch
    const uint32_t p4   = (tid & 4095u) << 2;                // position*4
    const uint32_t toff = bi * (uint32_t)(C_ * HW_) + p4;    // element offset (fits 32b)

    const float* xc = x;                                     // wave-uniform, advances by HW_
    f32x2 a0 = {0.f, 0.f};
    f32x2 a1 = {0.f, 0.f};

    #pragma unroll 8
    for (int c = 0; c < C_; ++c) {
        const f32x4 v  = __builtin_nontemporal_load(
                             reinterpret_cast<const f32x4*>(xc + toff));
        const float wc = w[c];                               // uniform -> s_load
        const f32x2 wp = {wc, wc};                           // SGPR pair
        f32x2 lo = __builtin_shufflevector(v, v, 0, 1);
        f32x2 hi = __builtin_shufflevector(v, v, 2, 3);
        asm("v_pk_fma_f32 %0, %1, %2, %0" : "+v"(a0) : "v"(lo), "s"(wp));
        asm("v_pk_fma_f32 %0, %1, %2, %0" : "+v"(a1) : "v"(hi), "s"(wp));
        xc += HW_;
    }

    const float bb = bias[0];
    f32x4 o;
    o[0] = fabsf(a0[0] + bb);
    o[1] = fabsf(a0[1] + bb);
    o[2] = fabsf(a1[0] + bb);
    o[3] = fabsf(a1[1] + bb);
    *reinterpret_cast<f32x4*>(scores + (bi * (uint32_t)HW_ + p4)) = o;
}

// ---------------------------------------------------------------------------
// Wave-parallel crossing-bin finder. hist has NB bins (NB in {2048, 512});
// finds bin B s.t. suffix_count(B+1) < k <= suffix_count(B).
// ---------------------------------------------------------------------------
template <int NB>
__device__ __forceinline__ void find_crossing(const uint32_t* hist, int k,
                                              int* sh_bin, int* sh_k, int tid) {
    constexpr int G = NB >> 6;                      // bins per lane (32 or 8)
    if (tid < 64) {
        const int lane = tid;
        uint32_t gs = 0;
        #pragma unroll
        for (int i = 0; i < G; ++i) {
            const int j = (i + lane) & (G - 1);     // rotate to spread banks
            gs += hist[lane * G + j];
        }
        // suffix sum across 64 lanes
        uint32_t s = gs;
        #pragma unroll
        for (int off = 1; off < 64; off <<= 1) {
            uint32_t t = __shfl_down(s, off);
            s += (lane + off < 64) ? t : 0u;
        }
        uint32_t snext = __shfl_down(s, 1);
        if (lane == 63) snext = 0u;
        const bool mine = (s >= (uint32_t)k) && (snext < (uint32_t)k);
        const unsigned long long bal = __ballot(mine);
        const int g = __ffsll(bal) - 1;             // winning group (uniform)
        const uint32_t above_g = __shfl(snext, g);  // count strictly above group g

        // stage 2: suffix scan of the G bins inside group g
        uint32_t hv = (lane < G) ? hist[g * G + lane] : 0u;
        uint32_t s2 = hv;
        #pragma unroll
        for (int off = 1; off < G; off <<= 1) {
            uint32_t t = __shfl_down(s2, off);
            s2 += (lane + off < G) ? t : 0u;
        }
        uint32_t s2next = __shfl_down(s2, 1);
        if (lane >= G - 1) s2next = 0u;
        const bool mine2 = (lane < G) &&
                           (above_g + s2 >= (uint32_t)k) &&
                           (above_g + s2next < (uint32_t)k);
        if (mine2) {
            *sh_bin = g * G + lane;
            *sh_k   = k - (int)(above_g + s2next);
        }
    }
    __syncthreads();
}

// ---------------------------------------------------------------------------
// Kernel 2: per-batch exact top-K mean. One block (1024 thr, 16 waves) per
// batch; each thread keeps 16 values in registers for all 3 radix passes.
// ---------------------------------------------------------------------------
__global__ __launch_bounds__(1024) void topk_mean_kernel(const float* __restrict__ scores,
                                                         float* __restrict__ out) {
    const int tid = threadIdx.x;
    const int b   = blockIdx.x;

    __shared__ uint32_t hist[2048];
    __shared__ float    sumc[512];
    __shared__ float    red[16];
    __shared__ int      sh_bin, sh_k;

    const uint4* sv = reinterpret_cast<const uint4*>(scores) + (size_t)b * (HW_ / 4);
    uint32_t r[16];
    {
        uint4 q;
        q = sv[tid];        r[0]  = q.x; r[1]  = q.y; r[2]  = q.z; r[3]  = q.w;
        q = sv[tid + 1024]; r[4]  = q.x; r[5]  = q.y; r[6]  = q.z; r[7]  = q.w;
        q = sv[tid + 2048]; r[8]  = q.x; r[9]  = q.y; r[10] = q.z; r[11] = q.w;
        q = sv[tid + 3072]; r[12] = q.x; r[13] = q.y; r[14] = q.z; r[15] = q.w;
    }

    hist[tid] = 0u; hist[tid + 1024] = 0u;
    __syncthreads();

    // ---- pass A: bits 30:20 ----
    #pragma unroll
    for (int i = 0; i < 16; ++i) atomicAdd(&hist[r[i] >> 20], 1u);
    __syncthreads();
    find_crossing<2048>(hist, K_TOP, &sh_bin, &sh_k, tid);
    const uint32_t B1 = (uint32_t)sh_bin;
    const int      k1 = sh_k;
    __syncthreads();

    hist[tid] = 0u; hist[tid + 1024] = 0u;
    __syncthreads();

    // ---- pass B: bits 19:9 among prefix-B1; accumulate sum above B1 ----
    float sAbove = 0.f;
    #pragma unroll
    for (int i = 0; i < 16; ++i) {
        const uint32_t u  = r[i];
        const uint32_t b1 = u >> 20;
        if (b1 > B1)       sAbove += __uint_as_float(u);
        else if (b1 == B1) atomicAdd(&hist[(u >> 9) & 2047u], 1u);
    }
    __syncthreads();
    find_crossing<2048>(hist, k1, &sh_bin, &sh_k, tid);
    const uint32_t B2 = (uint32_t)sh_bin;
    const int      k2 = sh_k;
    __syncthreads();

    if (tid < 512) { hist[tid] = 0u; sumc[tid] = 0.f; }
    __syncthreads();

    // ---- pass C: bits 8:0 among prefix-(B1,B2); counts + exact sums ----
    #pragma unroll
    for (int i = 0; i < 16; ++i) {
        const uint32_t u = r[i];
        if ((u >> 20) == B1) {
            const uint32_t b2 = (u >> 9) & 2047u;
            if (b2 > B2) sAbove += __uint_as_float(u);
            else if (b2 == B2) {
                const uint32_t b3 = u & 511u;
                atomicAdd(&hist[b3], 1u);
                atomicAdd(&sumc[b3], __uint_as_float(u));
            }
        }
    }
    __syncthreads();
    find_crossing<512>(hist, k2, &sh_bin, &sh_k, tid);
    const uint32_t B3 = (uint32_t)sh_bin;
    const int      k3 = sh_k;
    __syncthreads();

    if (tid < 512 && tid > (int)B3) sAbove += sumc[tid];

    #pragma unroll
    for (int off = 32; off > 0; off >>= 1) sAbove += __shfl_down(sAbove, off);
    if ((tid & 63) == 0) red[tid >> 6] = sAbove;
    __syncthreads();

    if (tid == 0) {
        float tot = 0.f;
        #pragma unroll
        for (int i = 0; i < 16; ++i) tot += red[i];
        const float T = __uint_as_float((B1 << 20) | (B2 << 9) | B3);
        out[b] = (tot + (float)k3 * T) / (float)K_TOP;
    }
}

// ---------------------------------------------------------------------------
extern "C" void kernel_launch(void* const* d_in, const int* in_sizes, int n_in,
                              void* d_out, int out_size, void* d_ws, size_t ws_size,
                              hipStream_t stream) {
    const float* x    = (const float*)d_in[0];   // [32,256,128,128]
    const float* w    = (const float*)d_in[1];   // [1,256,1,1] -> 256 floats
    const float* bias = (const float*)d_in[2];   // [1]
    float*       out  = (float*)d_out;           // [32,1]
    float*       scores = (float*)d_ws;          // 2 MiB scratch

    score_kernel<<<512, 256, 0, stream>>>(x, w, bias, scores);
    topk_mean_kernel<<<B_, 1024, 0, stream>>>(scores, out);
}